// Round 1
// baseline (652.002 us; speedup 1.0000x reference)
//
#include <hip/hip_runtime.h>
#include <hip/hip_bf16.h>
#include <stdint.h>

#define IN_F 4096
#define OUT_F 4096
#define RANK 16
#define LORA_SCALE 2.0f

typedef __attribute__((ext_vector_type(8))) short short8;
typedef __attribute__((ext_vector_type(4))) float f32x4;

__device__ __constant__ float NF4_CODE[16] = {
    -1.0f, -0.6961928009986877f, -0.5250730514526367f, -0.39491748809814453f,
    -0.28444138169288635f, -0.18477343022823334f, -0.09105003625154495f, 0.0f,
    0.07958029955625534f, 0.16093020141124725f, 0.24611230194568634f,
    0.33791524171829224f, 0.44070982933044434f, 0.5626170039176941f,
    0.7229568362236023f, 1.0f};

__device__ __forceinline__ short bf16_rne(float f) {
    uint32_t u = __builtin_bit_cast(uint32_t, f);
    u += 0x7fffu + ((u >> 16) & 1u);
    return (short)(u >> 16);
}

__device__ __forceinline__ void load_lds16(const short* g, short* l) {
    __builtin_amdgcn_global_load_lds(
        (const __attribute__((address_space(1))) void*)g,
        (__attribute__((address_space(3))) void*)l, 16, 0, 0);
}

// ---------------------------------------------------------------------------
// Prep 1: W_eff[o][i] = NF4[codes[o][i]] * absmax[o][i/64] + 2*(Wa@Wb)[i][o]
// written as bf16, [OUT_F][IN_F] row-major (the GEMM's B^T operand).
// 64(o) x 64(i) tile per block; one absmax block per (o, i-tile).
// ---------------------------------------------------------------------------
__global__ __launch_bounds__(256)
void dequant_fold(const int* __restrict__ codes, const float* __restrict__ am,
                  const float* __restrict__ Wa, const float* __restrict__ Wb,
                  short* __restrict__ Weff)
{
    __shared__ float WaT[RANK * 64];   // [r][i_local]  (transposed for vec reads)
    __shared__ float Wbs[RANK * 64];   // [r][o_local]

    const int tid   = threadIdx.x;
    const int iBase = blockIdx.x * 64;
    const int oBase = blockIdx.y * 64;

    {   // stage Wa rows iBase..iBase+63 (transpose) and Wb cols oBase..+63
        f32x4 v = *(const f32x4*)(Wa + (size_t)iBase * RANK + tid * 4);
        #pragma unroll
        for (int j = 0; j < 4; j++) {
            int e = tid * 4 + j;                 // e = i_local*16 + r
            WaT[(e & 15) * 64 + (e >> 4)] = v[j];
        }
        int r = tid >> 4, c = (tid & 15) * 4;
        f32x4 w = *(const f32x4*)(Wb + (size_t)r * OUT_F + oBase + c);
        *(f32x4*)&Wbs[r * 64 + c] = w;
    }
    __syncthreads();

    #pragma unroll
    for (int p = 0; p < 2; p++) {
        const int g  = tid + p * 256;   // 512 groups: 64 o-rows x 8 i-groups
        const int o  = g >> 3;
        const int ig = (g & 7) * 8;
        const float amax = am[(size_t)(oBase + o) * (IN_F / 64) + (iBase >> 6)];

        const int4* cp = (const int4*)(codes + (size_t)(oBase + o) * IN_F + iBase + ig);
        int4 c0 = cp[0], c1 = cp[1];
        int cc[8] = {c0.x, c0.y, c0.z, c0.w, c1.x, c1.y, c1.z, c1.w};

        float acc[8] = {0, 0, 0, 0, 0, 0, 0, 0};
        #pragma unroll
        for (int r = 0; r < RANK; r++) {
            float wb = Wbs[r * 64 + o];
            f32x4 a0 = *(const f32x4*)&WaT[r * 64 + ig];
            f32x4 a1 = *(const f32x4*)&WaT[r * 64 + ig + 4];
            acc[0] += a0[0] * wb;  acc[1] += a0[1] * wb;
            acc[2] += a0[2] * wb;  acc[3] += a0[3] * wb;
            acc[4] += a1[0] * wb;  acc[5] += a1[1] * wb;
            acc[6] += a1[2] * wb;  acc[7] += a1[3] * wb;
        }

        short8 out;
        #pragma unroll
        for (int j = 0; j < 8; j++)
            out[j] = bf16_rne(NF4_CODE[cc[j] & 15] * amax + LORA_SCALE * acc[j]);
        *(short8*)(Weff + (size_t)(oBase + o) * IN_F + iBase + ig) = out;
    }
}

// ---------------------------------------------------------------------------
// Prep 2: x fp32 -> bf16 (8 elements / thread)
// ---------------------------------------------------------------------------
__global__ __launch_bounds__(256)
void cast_x_kernel(const float* __restrict__ x, short* __restrict__ xb)
{
    const int i = blockIdx.x * blockDim.x + threadIdx.x;
    const f32x4* xv = (const f32x4*)x;
    f32x4 a = xv[2 * (size_t)i], b = xv[2 * (size_t)i + 1];
    short8 o;
    o[0] = bf16_rne(a[0]); o[1] = bf16_rne(a[1]);
    o[2] = bf16_rne(a[2]); o[3] = bf16_rne(a[3]);
    o[4] = bf16_rne(b[0]); o[5] = bf16_rne(b[1]);
    o[6] = bf16_rne(b[2]); o[7] = bf16_rne(b[3]);
    ((short8*)xb)[i] = o;
}

// ---------------------------------------------------------------------------
// Main GEMM: C[M][N] = A[M][K] * Bt[N][K]^T  (bf16 in, fp32 out)
// m97 structure: 128x128 tile / 256 thr / BK=32 / global_load_lds(16B) /
// mfma_f32_16x16x32_bf16, 4 waves each 64x64 (4x4 of 16x16).
// ABF16=false: A is fp32 (read-convert staging; no xb workspace needed).
// ---------------------------------------------------------------------------
template<bool ABF16>
__global__ __launch_bounds__(256)
void gemm_bt(const void* __restrict__ Ain, const short* __restrict__ Bt,
             float* __restrict__ C)
{
    __shared__ __align__(16) short lds[8192];   // A: [0,4096)  B: [4096,8192)
    short* sA = lds;
    short* sB = lds + 4096;

    const int tid   = threadIdx.x;
    const int lane  = tid & 63;
    const int wave  = tid >> 6;
    const int mBase = blockIdx.y * 128;
    const int nBase = blockIdx.x * 128;
    const int wm = (wave >> 1) * 64;
    const int wn = (wave & 1) * 64;

    const int srow = tid >> 2;        // staging slot row (0..63; +64 for p=1)
    const int scol = (tid & 3) * 8;   // k offset within BK

    const short* ag0 = nullptr; const short* ag1 = nullptr;
    const float* af0 = nullptr; const float* af1 = nullptr;
    if constexpr (ABF16) {
        const short* A = (const short*)Ain;
        ag0 = A + (size_t)(mBase + srow) * IN_F + scol;
        ag1 = A + (size_t)(mBase + 64 + srow) * IN_F + scol;
    } else {
        const float* A = (const float*)Ain;
        af0 = A + (size_t)(mBase + srow) * IN_F + scol;
        af1 = A + (size_t)(mBase + 64 + srow) * IN_F + scol;
    }
    const short* bg0 = Bt + (size_t)(nBase + srow) * IN_F + scol;
    const short* bg1 = Bt + (size_t)(nBase + 64 + srow) * IN_F + scol;

    short* sA0 = sA + tid * 8;          // lds dest = wave-uniform base + lane*16B
    short* sA1 = sA + (tid + 256) * 8;
    short* sB0 = sB + tid * 8;
    short* sB1 = sB + (tid + 256) * 8;

    const int fr = lane & 15;   // fragment row
    const int kg = lane >> 4;   // k-group 0..3

    f32x4 acc[4][4];
    #pragma unroll
    for (int i = 0; i < 4; i++)
        #pragma unroll
        for (int j = 0; j < 4; j++)
            acc[i][j] = (f32x4){0.f, 0.f, 0.f, 0.f};

    for (int k0 = 0; k0 < IN_F; k0 += 32) {
        if constexpr (ABF16) {
            load_lds16(ag0 + k0, sA0);
            load_lds16(ag1 + k0, sA1);
        } else {
            f32x4 v0 = *(const f32x4*)(af0 + k0);
            f32x4 v1 = *(const f32x4*)(af0 + k0 + 4);
            f32x4 v2 = *(const f32x4*)(af1 + k0);
            f32x4 v3 = *(const f32x4*)(af1 + k0 + 4);
            short8 o0, o1;
            #pragma unroll
            for (int j = 0; j < 4; j++) {
                o0[j]     = bf16_rne(v0[j]); o0[j + 4] = bf16_rne(v1[j]);
                o1[j]     = bf16_rne(v2[j]); o1[j + 4] = bf16_rne(v3[j]);
            }
            *(short8*)sA0 = o0;
            *(short8*)sA1 = o1;
        }
        load_lds16(bg0 + k0, sB0);
        load_lds16(bg1 + k0, sB1);
        __syncthreads();

        short8 a[4], b[4];
        #pragma unroll
        for (int i = 0; i < 4; i++)
            a[i] = *(const short8*)(sA + (wm + i * 16 + fr) * 32 + kg * 8);
        #pragma unroll
        for (int i = 0; i < 4; i++)
            b[i] = *(const short8*)(sB + (wn + i * 16 + fr) * 32 + kg * 8);

        #pragma unroll
        for (int mi = 0; mi < 4; mi++)
            #pragma unroll
            for (int ni = 0; ni < 4; ni++)
                acc[mi][ni] = __builtin_amdgcn_mfma_f32_16x16x32_bf16(
                    a[mi], b[ni], acc[mi][ni], 0, 0, 0);
        __syncthreads();
    }

    // epilogue: C/D layout col=lane&15, row=(lane>>4)*4+reg
    const int cr = (lane >> 4) * 4;
    const int cc = lane & 15;
    #pragma unroll
    for (int mi = 0; mi < 4; mi++) {
        #pragma unroll
        for (int ni = 0; ni < 4; ni++) {
            float* cp = C + (size_t)(mBase + wm + mi * 16 + cr) * OUT_F
                          + nBase + wn + ni * 16 + cc;
            #pragma unroll
            for (int j = 0; j < 4; j++)
                cp[(size_t)j * OUT_F] = acc[mi][ni][j];
        }
    }
}

// ---------------------------------------------------------------------------
extern "C" void kernel_launch(void* const* d_in, const int* in_sizes, int n_in,
                              void* d_out, int out_size, void* d_ws, size_t ws_size,
                              hipStream_t stream)
{
    const float* x     = (const float*)d_in[0];
    const int*   codes = (const int*)d_in[1];
    const float* am    = (const float*)d_in[2];
    const float* Wa    = (const float*)d_in[3];
    const float* Wb    = (const float*)d_in[4];
    float* out = (float*)d_out;

    const int M = in_sizes[0] / IN_F;   // 8192 tokens

    short* Weff = (short*)d_ws;                          // OUT_F*IN_F bf16
    short* xb   = Weff + (size_t)OUT_F * IN_F;           // M*IN_F bf16
    const size_t need_full =
        ((size_t)OUT_F * IN_F + (size_t)M * IN_F) * sizeof(short);

    dequant_fold<<<dim3(IN_F / 64, OUT_F / 64), 256, 0, stream>>>(
        codes, am, Wa, Wb, Weff);

    if (ws_size >= need_full) {
        const int ngrp = (M * IN_F) / 8;
        cast_x_kernel<<<ngrp / 256, 256, 0, stream>>>(x, xb);
        gemm_bt<true><<<dim3(OUT_F / 128, M / 128), 256, 0, stream>>>(
            xb, Weff, out);
    } else {
        gemm_bt<false><<<dim3(OUT_F / 128, M / 128), 256, 0, stream>>>(
            x, Weff, out);
    }
}

// Round 2
// 644.104 us; speedup vs baseline: 1.0123x; 1.0123x over previous
//
#include <hip/hip_runtime.h>
#include <hip/hip_bf16.h>
#include <stdint.h>

#define IN_F 4096
#define OUT_F 4096
#define RANK 16
#define LORA_SCALE 2.0f

typedef __attribute__((ext_vector_type(8))) short short8;
typedef __attribute__((ext_vector_type(4))) float f32x4;

__device__ __constant__ float NF4_CODE[16] = {
    -1.0f, -0.6961928009986877f, -0.5250730514526367f, -0.39491748809814453f,
    -0.28444138169288635f, -0.18477343022823334f, -0.09105003625154495f, 0.0f,
    0.07958029955625534f, 0.16093020141124725f, 0.24611230194568634f,
    0.33791524171829224f, 0.44070982933044434f, 0.5626170039176941f,
    0.7229568362236023f, 1.0f};

__device__ __forceinline__ short bf16_rne(float f) {
    uint32_t u = __builtin_bit_cast(uint32_t, f);
    u += 0x7fffu + ((u >> 16) & 1u);
    return (short)(u >> 16);
}

__device__ __forceinline__ void load_lds16(const short* g, short* l) {
    __builtin_amdgcn_global_load_lds(
        (const __attribute__((address_space(1))) void*)g,
        (__attribute__((address_space(3))) void*)l, 16, 0, 0);
}

// ---------------------------------------------------------------------------
// Prep 1: W_eff[o][i] = NF4[codes[o][i]] * absmax[o][i/64] + 2*(Wa@Wb)[i][o]
// written as bf16, [OUT_F][IN_F] row-major (the GEMM's B^T operand).
// ---------------------------------------------------------------------------
__global__ __launch_bounds__(256)
void dequant_fold(const int* __restrict__ codes, const float* __restrict__ am,
                  const float* __restrict__ Wa, const float* __restrict__ Wb,
                  short* __restrict__ Weff)
{
    __shared__ float WaT[RANK * 64];   // [r][i_local]
    __shared__ float Wbs[RANK * 64];   // [r][o_local]

    const int tid   = threadIdx.x;
    const int iBase = blockIdx.x * 64;
    const int oBase = blockIdx.y * 64;

    {
        f32x4 v = *(const f32x4*)(Wa + (size_t)iBase * RANK + tid * 4);
        #pragma unroll
        for (int j = 0; j < 4; j++) {
            int e = tid * 4 + j;                 // e = i_local*16 + r
            WaT[(e & 15) * 64 + (e >> 4)] = v[j];
        }
        int r = tid >> 4, c = (tid & 15) * 4;
        f32x4 w = *(const f32x4*)(Wb + (size_t)r * OUT_F + oBase + c);
        *(f32x4*)&Wbs[r * 64 + c] = w;
    }
    __syncthreads();

    #pragma unroll
    for (int p = 0; p < 2; p++) {
        const int g  = tid + p * 256;   // 512 groups: 64 o-rows x 8 i-groups
        const int o  = g >> 3;
        const int ig = (g & 7) * 8;
        const float amax = am[(size_t)(oBase + o) * (IN_F / 64) + (iBase >> 6)];

        const int4* cp = (const int4*)(codes + (size_t)(oBase + o) * IN_F + iBase + ig);
        int4 c0 = cp[0], c1 = cp[1];
        int cc[8] = {c0.x, c0.y, c0.z, c0.w, c1.x, c1.y, c1.z, c1.w};

        float acc[8] = {0, 0, 0, 0, 0, 0, 0, 0};
        #pragma unroll
        for (int r = 0; r < RANK; r++) {
            float wb = Wbs[r * 64 + o];
            f32x4 a0 = *(const f32x4*)&WaT[r * 64 + ig];
            f32x4 a1 = *(const f32x4*)&WaT[r * 64 + ig + 4];
            acc[0] += a0[0] * wb;  acc[1] += a0[1] * wb;
            acc[2] += a0[2] * wb;  acc[3] += a0[3] * wb;
            acc[4] += a1[0] * wb;  acc[5] += a1[1] * wb;
            acc[6] += a1[2] * wb;  acc[7] += a1[3] * wb;
        }

        short8 out;
        #pragma unroll
        for (int j = 0; j < 8; j++)
            out[j] = bf16_rne(NF4_CODE[cc[j] & 15] * amax + LORA_SCALE * acc[j]);
        *(short8*)(Weff + (size_t)(oBase + o) * IN_F + iBase + ig) = out;
    }
}

// ---------------------------------------------------------------------------
// Prep 2: x fp32 -> bf16 (8 elements / thread)
// ---------------------------------------------------------------------------
__global__ __launch_bounds__(256)
void cast_x_kernel(const float* __restrict__ x, short* __restrict__ xb)
{
    const int i = blockIdx.x * blockDim.x + threadIdx.x;
    const f32x4* xv = (const f32x4*)x;
    f32x4 a = xv[2 * (size_t)i], b = xv[2 * (size_t)i + 1];
    short8 o;
    o[0] = bf16_rne(a[0]); o[1] = bf16_rne(a[1]);
    o[2] = bf16_rne(a[2]); o[3] = bf16_rne(a[3]);
    o[4] = bf16_rne(b[0]); o[5] = bf16_rne(b[1]);
    o[6] = bf16_rne(b[2]); o[7] = bf16_rne(b[3]);
    ((short8*)xb)[i] = o;
}

// ---------------------------------------------------------------------------
// Main GEMM: C[M][N] = A[M][K] * Bt[N][K]^T  (bf16 in, fp32 out)
// m97 structure + XOR bank-swizzle: LDS row r, slot p holds global k-chunk
// p ^ ((r>>1)&3).  Staging permutes the global source (coalescing preserved
// within each 128B segment); fragment reads use chunk = kg ^ ((fr>>1)&3),
// which tiles all 8 LDS bank-groups exactly 2x per 16-lane phase -> 0
// conflicts (was 4-way: SQ_LDS_BANK_CONFLICT = 4.0 * ds_read count).
// ---------------------------------------------------------------------------
template<bool ABF16>
__global__ __launch_bounds__(256)
void gemm_bt(const void* __restrict__ Ain, const short* __restrict__ Bt,
             float* __restrict__ C)
{
    __shared__ __align__(16) short lds[8192];   // A: [0,4096)  B: [4096,8192)
    short* sA = lds;
    short* sB = lds + 4096;

    const int tid   = threadIdx.x;
    const int lane  = tid & 63;
    const int wave  = tid >> 6;
    const int mBase = blockIdx.y * 128;
    const int nBase = blockIdx.x * 128;
    const int wm = (wave >> 1) * 64;
    const int wn = (wave & 1) * 64;

    const int srow = tid >> 2;                        // staging row (0..63)
    const int q    = (tid & 3) ^ ((srow >> 1) & 3);   // swizzled global chunk
    const int scol = q * 8;                           // k offset within BK

    const short* ag0 = nullptr; const short* ag1 = nullptr;
    const float* af0 = nullptr; const float* af1 = nullptr;
    if constexpr (ABF16) {
        const short* A = (const short*)Ain;
        ag0 = A + (size_t)(mBase + srow) * IN_F + scol;
        ag1 = A + (size_t)(mBase + 64 + srow) * IN_F + scol;
    } else {
        const float* A = (const float*)Ain;
        af0 = A + (size_t)(mBase + srow) * IN_F + scol;
        af1 = A + (size_t)(mBase + 64 + srow) * IN_F + scol;
    }
    const short* bg0 = Bt + (size_t)(nBase + srow) * IN_F + scol;
    const short* bg1 = Bt + (size_t)(nBase + 64 + srow) * IN_F + scol;

    short* sA0 = sA + tid * 8;          // lds dest = wave-uniform base + lane*16B
    short* sA1 = sA + (tid + 256) * 8;
    short* sB0 = sB + tid * 8;
    short* sB1 = sB + (tid + 256) * 8;

    const int fr = lane & 15;           // fragment row
    const int kg = lane >> 4;           // k-group 0..3
    const int sw = (fr >> 1) & 3;       // row-swizzle (wm, i*16 are 0 mod 8)

    f32x4 acc[4][4];
    #pragma unroll
    for (int i = 0; i < 4; i++)
        #pragma unroll
        for (int j = 0; j < 4; j++)
            acc[i][j] = (f32x4){0.f, 0.f, 0.f, 0.f};

    for (int k0 = 0; k0 < IN_F; k0 += 32) {
        if constexpr (ABF16) {
            load_lds16(ag0 + k0, sA0);
            load_lds16(ag1 + k0, sA1);
        } else {
            f32x4 v0 = *(const f32x4*)(af0 + k0);
            f32x4 v1 = *(const f32x4*)(af0 + k0 + 4);
            f32x4 v2 = *(const f32x4*)(af1 + k0);
            f32x4 v3 = *(const f32x4*)(af1 + k0 + 4);
            short8 o0, o1;
            #pragma unroll
            for (int j = 0; j < 4; j++) {
                o0[j]     = bf16_rne(v0[j]); o0[j + 4] = bf16_rne(v1[j]);
                o1[j]     = bf16_rne(v2[j]); o1[j + 4] = bf16_rne(v3[j]);
            }
            *(short8*)sA0 = o0;
            *(short8*)sA1 = o1;
        }
        load_lds16(bg0 + k0, sB0);
        load_lds16(bg1 + k0, sB1);
        __syncthreads();

        short8 a[4], b[4];
        #pragma unroll
        for (int i = 0; i < 4; i++)
            a[i] = *(const short8*)(sA + (wm + i * 16 + fr) * 32 + (kg ^ sw) * 8);
        #pragma unroll
        for (int i = 0; i < 4; i++)
            b[i] = *(const short8*)(sB + (wn + i * 16 + fr) * 32 + (kg ^ sw) * 8);

        #pragma unroll
        for (int mi = 0; mi < 4; mi++)
            #pragma unroll
            for (int ni = 0; ni < 4; ni++)
                acc[mi][ni] = __builtin_amdgcn_mfma_f32_16x16x32_bf16(
                    a[mi], b[ni], acc[mi][ni], 0, 0, 0);
        __syncthreads();
    }

    // epilogue: C/D layout col=lane&15, row=(lane>>4)*4+reg
    const int cr = (lane >> 4) * 4;
    const int cc = lane & 15;
    #pragma unroll
    for (int mi = 0; mi < 4; mi++) {
        #pragma unroll
        for (int ni = 0; ni < 4; ni++) {
            float* cp = C + (size_t)(mBase + wm + mi * 16 + cr) * OUT_F
                          + nBase + wn + ni * 16 + cc;
            #pragma unroll
            for (int j = 0; j < 4; j++)
                cp[(size_t)j * OUT_F] = acc[mi][ni][j];
        }
    }
}

// ---------------------------------------------------------------------------
extern "C" void kernel_launch(void* const* d_in, const int* in_sizes, int n_in,
                              void* d_out, int out_size, void* d_ws, size_t ws_size,
                              hipStream_t stream)
{
    const float* x     = (const float*)d_in[0];
    const int*   codes = (const int*)d_in[1];
    const float* am    = (const float*)d_in[2];
    const float* Wa    = (const float*)d_in[3];
    const float* Wb    = (const float*)d_in[4];
    float* out = (float*)d_out;

    const int M = in_sizes[0] / IN_F;   // 8192 tokens

    short* Weff = (short*)d_ws;                          // OUT_F*IN_F bf16
    short* xb   = Weff + (size_t)OUT_F * IN_F;           // M*IN_F bf16
    const size_t need_full =
        ((size_t)OUT_F * IN_F + (size_t)M * IN_F) * sizeof(short);

    dequant_fold<<<dim3(IN_F / 64, OUT_F / 64), 256, 0, stream>>>(
        codes, am, Wa, Wb, Weff);

    if (ws_size >= need_full) {
        const int ngrp = (M * IN_F) / 8;
        cast_x_kernel<<<ngrp / 256, 256, 0, stream>>>(x, xb);
        gemm_bt<true><<<dim3(OUT_F / 128, M / 128), 256, 0, stream>>>(
            xb, Weff, out);
    } else {
        gemm_bt<false><<<dim3(OUT_F / 128, M / 128), 256, 0, stream>>>(
            x, Weff, out);
    }
}

// Round 3
// 539.704 us; speedup vs baseline: 1.2081x; 1.1934x over previous
//
#include <hip/hip_runtime.h>
#include <hip/hip_bf16.h>
#include <stdint.h>

#define IN_F 4096
#define OUT_F 4096
#define RANK 16
#define LORA_SCALE 2.0f

typedef __attribute__((ext_vector_type(8))) short short8;
typedef __attribute__((ext_vector_type(4))) float f32x4;
typedef __attribute__((ext_vector_type(16))) float f32x16;

__device__ __constant__ float NF4_CODE[16] = {
    -1.0f, -0.6961928009986877f, -0.5250730514526367f, -0.39491748809814453f,
    -0.28444138169288635f, -0.18477343022823334f, -0.09105003625154495f, 0.0f,
    0.07958029955625534f, 0.16093020141124725f, 0.24611230194568634f,
    0.33791524171829224f, 0.44070982933044434f, 0.5626170039176941f,
    0.7229568362236023f, 1.0f};

__device__ __forceinline__ short bf16_rne(float f) {
    uint32_t u = __builtin_bit_cast(uint32_t, f);
    u += 0x7fffu + ((u >> 16) & 1u);
    return (short)(u >> 16);
}

__device__ __forceinline__ void load_lds16(const short* g, short* l) {
    __builtin_amdgcn_global_load_lds(
        (const __attribute__((address_space(1))) void*)g,
        (__attribute__((address_space(3))) void*)l, 16, 0, 0);
}

// ---------------------------------------------------------------------------
// Fused prep (one launch):
//   blocks [0,4096):       W_eff[o][i] = NF4[codes]*absmax + 2*(Wa@Wb)^T  (bf16)
//   blocks [4096,4096+Nc): x fp32 -> bf16 cast, 2048 elems/block
// ---------------------------------------------------------------------------
__global__ __launch_bounds__(256)
void prep_kernel(const int* __restrict__ codes, const float* __restrict__ am,
                 const float* __restrict__ Wa, const float* __restrict__ Wb,
                 const float* __restrict__ x, short* __restrict__ Weff,
                 short* __restrict__ xb)
{
    const int tid = threadIdx.x;

    if (blockIdx.x >= 4096) {
        const size_t i = (size_t)(blockIdx.x - 4096) * 256 + tid;
        const f32x4* xv = (const f32x4*)x;
        f32x4 a = xv[2 * i], b = xv[2 * i + 1];
        short8 o;
        o[0] = bf16_rne(a[0]); o[1] = bf16_rne(a[1]);
        o[2] = bf16_rne(a[2]); o[3] = bf16_rne(a[3]);
        o[4] = bf16_rne(b[0]); o[5] = bf16_rne(b[1]);
        o[6] = bf16_rne(b[2]); o[7] = bf16_rne(b[3]);
        ((short8*)xb)[i] = o;
        return;
    }

    __shared__ float WaT[RANK * 64];   // [r][i_local]
    __shared__ float Wbs[RANK * 64];   // [r][o_local]

    const int iBase = (blockIdx.x & 63) * 64;
    const int oBase = (blockIdx.x >> 6) * 64;

    {
        f32x4 v = *(const f32x4*)(Wa + (size_t)iBase * RANK + tid * 4);
        #pragma unroll
        for (int j = 0; j < 4; j++) {
            int e = tid * 4 + j;                 // e = i_local*16 + r
            WaT[(e & 15) * 64 + (e >> 4)] = v[j];
        }
        int r = tid >> 4, c = (tid & 15) * 4;
        f32x4 w = *(const f32x4*)(Wb + (size_t)r * OUT_F + oBase + c);
        *(f32x4*)&Wbs[r * 64 + c] = w;
    }
    __syncthreads();

    #pragma unroll
    for (int p = 0; p < 2; p++) {
        const int g  = tid + p * 256;   // 512 groups: 64 o-rows x 8 i-groups
        const int o  = g >> 3;
        const int ig = (g & 7) * 8;
        const float amax = am[(size_t)(oBase + o) * (IN_F / 64) + (iBase >> 6)];

        const int4* cp = (const int4*)(codes + (size_t)(oBase + o) * IN_F + iBase + ig);
        int4 c0 = cp[0], c1 = cp[1];
        int cc[8] = {c0.x, c0.y, c0.z, c0.w, c1.x, c1.y, c1.z, c1.w};

        float acc[8] = {0, 0, 0, 0, 0, 0, 0, 0};
        #pragma unroll
        for (int r = 0; r < RANK; r++) {
            float wb = Wbs[r * 64 + o];
            f32x4 a0 = *(const f32x4*)&WaT[r * 64 + ig];
            f32x4 a1 = *(const f32x4*)&WaT[r * 64 + ig + 4];
            acc[0] += a0[0] * wb;  acc[1] += a0[1] * wb;
            acc[2] += a0[2] * wb;  acc[3] += a0[3] * wb;
            acc[4] += a1[0] * wb;  acc[5] += a1[1] * wb;
            acc[6] += a1[2] * wb;  acc[7] += a1[3] * wb;
        }

        short8 out;
        #pragma unroll
        for (int j = 0; j < 8; j++)
            out[j] = bf16_rne(NF4_CODE[cc[j] & 15] * amax + LORA_SCALE * acc[j]);
        *(short8*)(Weff + (size_t)(oBase + o) * IN_F + iBase + ig) = out;
    }
}

// ---------------------------------------------------------------------------
// Main GEMM: C[M][N] = A[M][K] * Bt[N][K]^T  (bf16 in, fp32 out)
// 128x128 tile / 256 thr / BK=64 / mfma_f32_32x32x16_bf16, 4 waves each
// 64x64 (2x2 of 32x32).  XOR bank-swizzle: LDS slot (row, sl) holds global
// k-chunk sl^(row&7); fragment read chunk c at slot c^(lane&7) -> lanes 0..7
// tile all 32 banks exactly once per 8-lane phase (conflict-free).
// A-frag: row=lane&31, k=(lane>>5)*8+j (symmetric ext. of verified 16x16x32).
// C/D:    col=lane&31, row=(reg&3)+8*(reg>>2)+4*(lane>>5)  [m74/m101].
// ---------------------------------------------------------------------------
template<bool ABF16>
__global__ __launch_bounds__(256)
void gemm32(const void* __restrict__ Ain, const short* __restrict__ Bt,
            float* __restrict__ C)
{
    __shared__ __align__(16) short lds[16384];  // A:[0,8192) B:[8192,16384)
    short* sA = lds;
    short* sB = lds + 8192;

    const int tid  = threadIdx.x;
    const int lane = tid & 63;
    const int wave = tid >> 6;
    const int mBase = blockIdx.y * 128;
    const int nBase = blockIdx.x * 128;
    const int wm = (wave >> 1) * 64;
    const int wn = (wave & 1) * 64;

    // staging: issue p covers rows p*32..p*32+31; thread t -> row p*32+(t>>3),
    // swizzled chunk (t&7)^(t>>3 & 7); LDS dest forced to (p*256+t)*16B.
    const int srow = tid >> 3;                  // 0..31
    const int scol = ((tid & 7) ^ (srow & 7)) * 8;

    const short* gA[4]; const float* fA[4]; const short* gB[4];
    #pragma unroll
    for (int p = 0; p < 4; p++) {
        if constexpr (ABF16)
            gA[p] = (const short*)Ain + (size_t)(mBase + p * 32 + srow) * IN_F + scol;
        else
            fA[p] = (const float*)Ain + (size_t)(mBase + p * 32 + srow) * IN_F + scol;
        gB[p] = Bt + (size_t)(nBase + p * 32 + srow) * IN_F + scol;
    }
    short* dA[4]; short* dB[4];
    #pragma unroll
    for (int p = 0; p < 4; p++) {
        dA[p] = sA + (p * 256 + tid) * 8;
        dB[p] = sB + (p * 256 + tid) * 8;
    }

    // fragment addressing
    const int l31 = lane & 31;
    const int h   = lane >> 5;
    const int r7  = lane & 7;
    int xo[4];
    #pragma unroll
    for (int s = 0; s < 4; s++) xo[s] = ((s * 2 + h) ^ r7) * 8;
    const int rA0 = (wm + l31) * 64, rA1 = rA0 + 32 * 64;
    const int rB0 = (wn + l31) * 64, rB1 = rB0 + 32 * 64;

    f32x16 acc[2][2];
    #pragma unroll
    for (int i = 0; i < 2; i++)
        #pragma unroll
        for (int j = 0; j < 2; j++)
            #pragma unroll
            for (int r = 0; r < 16; r++)
                acc[i][j][r] = 0.f;

    for (int k0 = 0; k0 < IN_F; k0 += 64) {
        if constexpr (ABF16) {
            #pragma unroll
            for (int p = 0; p < 4; p++) load_lds16(gA[p] + k0, dA[p]);
        } else {
            #pragma unroll
            for (int p = 0; p < 4; p++) {
                const float* s0 = fA[p] + k0;
                f32x4 v0 = *(const f32x4*)s0;
                f32x4 v1 = *(const f32x4*)(s0 + 4);
                short8 o;
                #pragma unroll
                for (int j = 0; j < 4; j++) {
                    o[j] = bf16_rne(v0[j]); o[j + 4] = bf16_rne(v1[j]);
                }
                *(short8*)dA[p] = o;
            }
        }
        #pragma unroll
        for (int p = 0; p < 4; p++) load_lds16(gB[p] + k0, dB[p]);
        __syncthreads();

        #pragma unroll
        for (int s = 0; s < 4; s++) {
            short8 a0 = *(const short8*)(sA + rA0 + xo[s]);
            short8 a1 = *(const short8*)(sA + rA1 + xo[s]);
            short8 b0 = *(const short8*)(sB + rB0 + xo[s]);
            short8 b1 = *(const short8*)(sB + rB1 + xo[s]);
            acc[0][0] = __builtin_amdgcn_mfma_f32_32x32x16_bf16(a0, b0, acc[0][0], 0, 0, 0);
            acc[0][1] = __builtin_amdgcn_mfma_f32_32x32x16_bf16(a0, b1, acc[0][1], 0, 0, 0);
            acc[1][0] = __builtin_amdgcn_mfma_f32_32x32x16_bf16(a1, b0, acc[1][0], 0, 0, 0);
            acc[1][1] = __builtin_amdgcn_mfma_f32_32x32x16_bf16(a1, b1, acc[1][1], 0, 0, 0);
        }
        __syncthreads();
    }

    // epilogue
    #pragma unroll
    for (int mi = 0; mi < 2; mi++) {
        #pragma unroll
        for (int ni = 0; ni < 2; ni++) {
            const int col  = nBase + wn + ni * 32 + l31;
            const int rowb = mBase + wm + mi * 32 + 4 * h;
            #pragma unroll
            for (int r = 0; r < 16; r++) {
                const int row = rowb + (r & 3) + 8 * (r >> 2);
                C[(size_t)row * OUT_F + col] = acc[mi][ni][r];
            }
        }
    }
}

// ---------------------------------------------------------------------------
extern "C" void kernel_launch(void* const* d_in, const int* in_sizes, int n_in,
                              void* d_out, int out_size, void* d_ws, size_t ws_size,
                              hipStream_t stream)
{
    const float* x     = (const float*)d_in[0];
    const int*   codes = (const int*)d_in[1];
    const float* am    = (const float*)d_in[2];
    const float* Wa    = (const float*)d_in[3];
    const float* Wb    = (const float*)d_in[4];
    float* out = (float*)d_out;

    const int M = in_sizes[0] / IN_F;   // 8192 tokens

    short* Weff = (short*)d_ws;                          // OUT_F*IN_F bf16
    short* xb   = Weff + (size_t)OUT_F * IN_F;           // M*IN_F bf16
    const size_t need_full =
        ((size_t)OUT_F * IN_F + (size_t)M * IN_F) * sizeof(short);

    if (ws_size >= need_full) {
        const int castBlocks = (M * IN_F / 8) / 256;
        prep_kernel<<<4096 + castBlocks, 256, 0, stream>>>(
            codes, am, Wa, Wb, x, Weff, xb);
        gemm32<true><<<dim3(OUT_F / 128, M / 128), 256, 0, stream>>>(
            xb, Weff, out);
    } else {
        prep_kernel<<<4096, 256, 0, stream>>>(
            codes, am, Wa, Wb, x, Weff, Weff /*unused*/);
        gemm32<false><<<dim3(OUT_F / 128, M / 128), 256, 0, stream>>>(
            x, Weff, out);
    }
}